// Round 2
// 696.255 us; speedup vs baseline: 1.1432x; 1.1432x over previous
//
#include <hip/hip_runtime.h>
#include <hip/hip_bf16.h>

#define N_NODES_C  1000000
#define N_GRAPHS_C 16384
#define NF   128      // node features
#define GF   64       // global features
#define HID  64       // hidden
#define TB   128      // nodes per block (scores kernel)
#define XMAX 128      // fallback LDS chunk
#define XSTR 136      // LDS row stride in bf16 elems

typedef __bf16 bf16x8 __attribute__((ext_vector_type(8)));
typedef __bf16 bf16x4 __attribute__((ext_vector_type(4)));
typedef float  floatx4 __attribute__((ext_vector_type(4)));

// ---------------- fused prep kernel ----------------
// blocks [0,2064):   zero z+Npool (528384 float4, exact)
// blocks [2064,2096): W1[0:128][0:64] -> bf16 transposed [n][k] (8192 elems, exact)
// blocks [2096,6192): hbase[g][n] = b1[n] + u[g] @ W1[128:192][n]   (4 graphs/block)
__global__ __launch_bounds__(256)
void prep_fused_kernel(const float* __restrict__ u, const float* __restrict__ W1,
                       const float* __restrict__ b1, floatx4* __restrict__ zero4,
                       __bf16* __restrict__ g_w1t, float* __restrict__ hbase){
  __shared__ float w1u[GF * HID];
  __shared__ float ush[4 * GF];
  const int bid = blockIdx.x;
  const int tid = threadIdx.x;
  if (bid < 2064){
    floatx4 zv = {0.f, 0.f, 0.f, 0.f};
    zero4[bid * 256 + tid] = zv;
    return;
  }
  if (bid < 2096){
    int idx = (bid - 2064) * 256 + tid;
    int n = idx >> 7, k = idx & 127;
    g_w1t[n * NF + k] = (__bf16)W1[k * HID + n];
    return;
  }
  const int g0 = (bid - 2096) * 4;
  for (int idx = tid; idx < GF * HID; idx += 256)
    w1u[idx] = W1[(NF + (idx >> 6)) * HID + (idx & 63)];
  { int gl = tid >> 6, k = tid & 63;
    ush[tid] = u[(size_t)(g0 + gl) * GF + k]; }
  __syncthreads();
  const int gl = tid >> 6, n = tid & 63;
  float h = b1[n];
  const float* ug = ush + gl * GF;
  #pragma unroll 8
  for (int k = 0; k < GF; k++) h = fmaf(ug[k], w1u[k * HID + n], h);
  hbase[(size_t)(g0 + gl) * HID + n] = h;
}

// ---------------- main streaming kernel ----------------
// Blocks own 128 consecutive nodes. One x read total:
//   e_i = exp(relu(x_i@W1x + hbase[g_i])@W2 + b2)  -> attn_e[i]
//   segmented in-block pooling: z[g] += sum e_i, Npool[g][f] += sum e_i x_i[f]
//   (plain stores for segments fully interior to the block; atomics only at edges)
__global__ __launch_bounds__(256, 3)
void scores_kernel(const float* __restrict__ x, const int* __restrict__ batch,
                   const __bf16* __restrict__ g_w1t, const float* __restrict__ hbase,
                   const float* __restrict__ W2, const float* __restrict__ b2,
                   float* __restrict__ z, float* __restrict__ Npool,
                   float* __restrict__ attn_e){
  __shared__ alignas(16) __bf16 x_lds[TB * XSTR];   // 34816 B
  __shared__ alignas(16) __bf16 w1t[HID * XSTR];    // 17408 B; aliased as pool_red later
  __shared__ float s_lds[TB];                       // e values
  __shared__ int   batch_l[TB];
  __shared__ float w2l[HID];
  __shared__ float zred[4];
  __shared__ unsigned long long mask_sh[2];

  const int tid = threadIdx.x;
  const int n0 = blockIdx.x * TB;
  const int cnt = min(TB, N_NODES_C - n0);

  // stage W1t (bf16, pre-transposed in ws) -> LDS, vectorized
  #pragma unroll
  for (int r2 = 0; r2 < 4; r2++){
    int idx = tid + r2 * 256;            // 0..1023
    int n = idx >> 4, c8 = idx & 15;
    *(bf16x8*)(w1t + n * XSTR + c8 * 8) = *(const bf16x8*)(g_w1t + n * NF + c8 * 8);
  }
  if (tid < TB) batch_l[tid] = batch[n0 + min(tid, cnt - 1)];
  if (tid < HID) w2l[tid] = W2[tid];

  // prefetch x rows (16 independent float4/thread in 2 waves of 8), convert to bf16 LDS
  // nontemporal: x is streamed once, keep L2 for hbase/z/Npool atomic working set
  const floatx4* x4 = (const floatx4*)x;
  #pragma unroll
  for (int h = 0; h < 2; h++){
    floatx4 buf[8];
    #pragma unroll
    for (int r = 0; r < 8; r++){
      int idx = tid + (h * 8 + r) * 256;
      int row = idx >> 5, c4 = idx & 31;
      int grow = min(row, cnt - 1);
      buf[r] = __builtin_nontemporal_load(&x4[(size_t)(n0 + grow) * 32 + c4]);
    }
    #pragma unroll
    for (int r = 0; r < 8; r++){
      int idx = tid + (h * 8 + r) * 256;
      int row = idx >> 5, c4 = idx & 31;
      bf16x4 b;
      b.x = (__bf16)buf[r][0]; b.y = (__bf16)buf[r][1];
      b.z = (__bf16)buf[r][2]; b.w = (__bf16)buf[r][3];
      *(bf16x4*)(x_lds + row * XSTR + c4 * 4) = b;
    }
  }
  __syncthreads();

  // MFMA: s -> e (z accumulation moved to segmented pooling phase)
  const int wid = tid >> 6, lane = tid & 63;
  const int l15 = lane & 15, q = lane >> 4;
  const float b2v = b2[0];
  const int padded = (cnt + 15) & ~15;
  for (int i0 = wid * 16; i0 < padded; i0 += 64){
    const int r0 = i0 + q * 4;
    int gid0 = batch_l[r0 + 0], gid1 = batch_l[r0 + 1];
    int gid2 = batch_l[r0 + 2], gid3 = batch_l[r0 + 3];
    const float* hb0 = hbase + (size_t)gid0 * HID + l15;
    const float* hb1 = hbase + (size_t)gid1 * HID + l15;
    const float* hb2 = hbase + (size_t)gid2 * HID + l15;
    const float* hb3 = hbase + (size_t)gid3 * HID + l15;
    floatx4 acc0, acc1, acc2, acc3;
    acc0[0]=hb0[0];  acc1[0]=hb0[16]; acc2[0]=hb0[32]; acc3[0]=hb0[48];
    acc0[1]=hb1[0];  acc1[1]=hb1[16]; acc2[1]=hb1[32]; acc3[1]=hb1[48];
    acc0[2]=hb2[0];  acc1[2]=hb2[16]; acc2[2]=hb2[32]; acc3[2]=hb2[48];
    acc0[3]=hb3[0];  acc1[3]=hb3[16]; acc2[3]=hb3[32]; acc3[3]=hb3[48];
    const __bf16* arow = x_lds + (i0 + l15) * XSTR + q * 8;
    const __bf16* br0 = w1t + ( 0 + l15) * XSTR + q * 8;
    const __bf16* br1 = w1t + (16 + l15) * XSTR + q * 8;
    const __bf16* br2 = w1t + (32 + l15) * XSTR + q * 8;
    const __bf16* br3 = w1t + (48 + l15) * XSTR + q * 8;
    #pragma unroll
    for (int ks = 0; ks < 4; ks++){
      bf16x8 a = *(const bf16x8*)(arow + ks * 32);
      acc0 = __builtin_amdgcn_mfma_f32_16x16x32_bf16(a, *(const bf16x8*)(br0 + ks * 32), acc0, 0, 0, 0);
      acc1 = __builtin_amdgcn_mfma_f32_16x16x32_bf16(a, *(const bf16x8*)(br1 + ks * 32), acc1, 0, 0, 0);
      acc2 = __builtin_amdgcn_mfma_f32_16x16x32_bf16(a, *(const bf16x8*)(br2 + ks * 32), acc2, 0, 0, 0);
      acc3 = __builtin_amdgcn_mfma_f32_16x16x32_bf16(a, *(const bf16x8*)(br3 + ks * 32), acc3, 0, 0, 0);
    }
    float w0 = w2l[ 0 + l15], w1v = w2l[16 + l15], w2v = w2l[32 + l15], w3v = w2l[48 + l15];
    float p0 = fmaxf(acc0[0],0.f)*w0 + fmaxf(acc1[0],0.f)*w1v + fmaxf(acc2[0],0.f)*w2v + fmaxf(acc3[0],0.f)*w3v;
    float p1 = fmaxf(acc0[1],0.f)*w0 + fmaxf(acc1[1],0.f)*w1v + fmaxf(acc2[1],0.f)*w2v + fmaxf(acc3[1],0.f)*w3v;
    float p2 = fmaxf(acc0[2],0.f)*w0 + fmaxf(acc1[2],0.f)*w1v + fmaxf(acc2[2],0.f)*w2v + fmaxf(acc3[2],0.f)*w3v;
    float p3 = fmaxf(acc0[3],0.f)*w0 + fmaxf(acc1[3],0.f)*w1v + fmaxf(acc2[3],0.f)*w2v + fmaxf(acc3[3],0.f)*w3v;
    #pragma unroll
    for (int m = 1; m < 16; m <<= 1){
      p0 += __shfl_xor(p0, m, 64);
      p1 += __shfl_xor(p1, m, 64);
      p2 += __shfl_xor(p2, m, 64);
      p3 += __shfl_xor(p3, m, 64);
    }
    if (l15 == 0){
      float e0 = __expf(p0 + b2v), e1 = __expf(p1 + b2v);
      float e2 = __expf(p2 + b2v), e3 = __expf(p3 + b2v);
      if (r0 + 3 < cnt){
        s_lds[r0+0] = e0; s_lds[r0+1] = e1; s_lds[r0+2] = e2; s_lds[r0+3] = e3;
        floatx4 ev = {e0, e1, e2, e3};
        __builtin_nontemporal_store(ev, (floatx4*)(attn_e + n0 + r0));
      } else {
        if (r0 + 0 < cnt){ s_lds[r0+0] = e0; attn_e[n0+r0+0] = e0; }
        if (r0 + 1 < cnt){ s_lds[r0+1] = e1; attn_e[n0+r0+1] = e1; }
        if (r0 + 2 < cnt){ s_lds[r0+2] = e2; attn_e[n0+r0+2] = e2; }
        if (r0 + 3 < cnt){ s_lds[r0+3] = e3; attn_e[n0+r0+3] = e3; }
      }
    }
  }
  __syncthreads();

  // segmented numerator + denominator pooling; boundaries via ballot masks
  bool flag = (tid > 0) && (tid < cnt) && (batch_l[tid] != batch_l[tid - 1]);
  unsigned long long bm = __ballot(flag);
  if (lane == 0 && wid < 2) mask_sh[wid] = bm;
  __syncthreads();
  unsigned long long m0 = mask_sh[0], m1 = mask_sh[1];
  float* pool_red = (float*)w1t;   // w1t dead after MFMA phase
  const int f2 = tid & 63, grp = tid >> 6;
  int a = 0;
  while (a < cnt){
    int b;
    if (m0){ b = __ffsll(m0) - 1; m0 &= m0 - 1; }
    else if (m1){ b = 64 + __ffsll(m1) - 1; m1 &= m1 - 1; }
    else b = cnt;
    const int g = batch_l[a];
    float p0 = 0.f, p1 = 0.f, es = 0.f;
    for (int i = a + grp; i < b; i += 4){
      float e = s_lds[i];
      es += e;
      unsigned w = *(const unsigned*)(x_lds + i * XSTR + 2 * f2);
      p0 = fmaf(e, __uint_as_float(w << 16), p0);
      p1 = fmaf(e, __uint_as_float(w & 0xffff0000u), p1);
    }
    pool_red[grp * NF + 2 * f2]     = p0;
    pool_red[grp * NF + 2 * f2 + 1] = p1;
    if (f2 == 0) zred[grp] = es;
    __syncthreads();
    // segment fully interior to this block (sorted batch) -> exclusive -> plain store
    const bool interior = (a > 0) && (b < cnt);
    if (tid < NF){
      float v = (pool_red[tid] + pool_red[NF + tid]) +
                (pool_red[2 * NF + tid] + pool_red[3 * NF + tid]);
      if (interior) Npool[(size_t)g * NF + tid] = v;
      else          atomicAdd(&Npool[(size_t)g * NF + tid], v);
    } else if (tid == NF){
      float zs = (zred[0] + zred[1]) + (zred[2] + zred[3]);
      if (interior) z[g] = zs;
      else          atomicAdd(&z[g], zs);
    }
    __syncthreads();
    a = b;
  }
}

// ---------------- fused finalize ----------------
// blocks [0,3907):      attn[i] = e_i / z[batch[i]]      (1M nodes)
// blocks [3907,12099):  pooled[i] = Npool[i] / z[i>>7]   (2.097M elems, exact)
__global__ __launch_bounds__(256)
void finalize_fused_kernel(const int* __restrict__ batch, const float* __restrict__ z,
                           const float* __restrict__ Npool, float* __restrict__ attn,
                           float* __restrict__ pooled){
  const int bid = blockIdx.x;
  const int tid = threadIdx.x;
  if (bid < 3907){
    int i = bid * 256 + tid;
    if (i < N_NODES_C){
      float e = __builtin_nontemporal_load(&attn[i]);
      __builtin_nontemporal_store(e / z[batch[i]], &attn[i]);
    }
  } else {
    int i = (bid - 3907) * 256 + tid;
    float zz = z[i >> 7];
    float v = (zz > 0.f) ? __builtin_nontemporal_load(&Npool[i]) / zz : 0.f;
    __builtin_nontemporal_store(v, &pooled[i]);
  }
}

// ---------------- fallback (ws too small): round-2 fused per-graph kernel ----------------

__device__ __forceinline__ int lower_bound_i(const int* __restrict__ a, int n, int key){
  int lo = 0, hi = n;
  while (lo < hi){ int mid = (lo + hi) >> 1; if (a[mid] < key) lo = mid + 1; else hi = mid; }
  return lo;
}

__device__ __forceinline__ float block_max(float v, float* red, int tid){
  #pragma unroll
  for (int m = 32; m >= 1; m >>= 1) v = fmaxf(v, __shfl_xor(v, m, 64));
  __syncthreads();
  if ((tid & 63) == 0) red[tid >> 6] = v;
  __syncthreads();
  return fmaxf(fmaxf(red[0], red[1]), fmaxf(red[2], red[3]));
}

__device__ __forceinline__ float block_sum(float v, float* red, int tid){
  #pragma unroll
  for (int m = 32; m >= 1; m >>= 1) v += __shfl_xor(v, m, 64);
  __syncthreads();
  if ((tid & 63) == 0) red[tid >> 6] = v;
  __syncthreads();
  return (red[0] + red[1]) + (red[2] + red[3]);
}

__device__ __forceinline__ void load_x_chunk(const floatx4* __restrict__ x4, int node0, int cnt,
                                             __bf16* x_lds, int tid){
  int padded = (cnt + 15) & ~15;
  for (int idx = tid; idx < padded * 32; idx += 256){
    int row = idx >> 5, c4 = idx & 31;
    floatx4 v = {0.f, 0.f, 0.f, 0.f};
    if (row < cnt) v = x4[(size_t)(node0 + row) * 32 + c4];
    bf16x4 b;
    b.x = (__bf16)v[0]; b.y = (__bf16)v[1]; b.z = (__bf16)v[2]; b.w = (__bf16)v[3];
    *(bf16x4*)(x_lds + row * XSTR + c4 * 4) = b;
  }
}

__device__ __forceinline__ void compute_s_chunk(const __bf16* x_lds, const __bf16* w1t,
    const float* hb_l, const float* w2l, float b2v, float* s_lds, int cnt, int tid){
  const int wid = tid >> 6, lane = tid & 63;
  const int l15 = lane & 15, q = lane >> 4;
  const int padded = (cnt + 15) & ~15;
  for (int i0 = wid * 16; i0 < padded; i0 += 64){
    floatx4 acc0, acc1, acc2, acc3;
    { float h;
      h = hb_l[ 0 + l15]; acc0[0]=h; acc0[1]=h; acc0[2]=h; acc0[3]=h;
      h = hb_l[16 + l15]; acc1[0]=h; acc1[1]=h; acc1[2]=h; acc1[3]=h;
      h = hb_l[32 + l15]; acc2[0]=h; acc2[1]=h; acc2[2]=h; acc2[3]=h;
      h = hb_l[48 + l15]; acc3[0]=h; acc3[1]=h; acc3[2]=h; acc3[3]=h; }
    const __bf16* arow = x_lds + (i0 + l15) * XSTR + q * 8;
    const __bf16* br0 = w1t + ( 0 + l15) * XSTR + q * 8;
    const __bf16* br1 = w1t + (16 + l15) * XSTR + q * 8;
    const __bf16* br2 = w1t + (32 + l15) * XSTR + q * 8;
    const __bf16* br3 = w1t + (48 + l15) * XSTR + q * 8;
    #pragma unroll
    for (int ks = 0; ks < 4; ks++){
      bf16x8 a = *(const bf16x8*)(arow + ks * 32);
      acc0 = __builtin_amdgcn_mfma_f32_16x16x32_bf16(a, *(const bf16x8*)(br0 + ks * 32), acc0, 0, 0, 0);
      acc1 = __builtin_amdgcn_mfma_f32_16x16x32_bf16(a, *(const bf16x8*)(br1 + ks * 32), acc1, 0, 0, 0);
      acc2 = __builtin_amdgcn_mfma_f32_16x16x32_bf16(a, *(const bf16x8*)(br2 + ks * 32), acc2, 0, 0, 0);
      acc3 = __builtin_amdgcn_mfma_f32_16x16x32_bf16(a, *(const bf16x8*)(br3 + ks * 32), acc3, 0, 0, 0);
    }
    float w0 = w2l[ 0 + l15], w1v = w2l[16 + l15], w2v = w2l[32 + l15], w3v = w2l[48 + l15];
    float p0 = fmaxf(acc0[0],0.f)*w0 + fmaxf(acc1[0],0.f)*w1v + fmaxf(acc2[0],0.f)*w2v + fmaxf(acc3[0],0.f)*w3v;
    float p1 = fmaxf(acc0[1],0.f)*w0 + fmaxf(acc1[1],0.f)*w1v + fmaxf(acc2[1],0.f)*w2v + fmaxf(acc3[1],0.f)*w3v;
    float p2 = fmaxf(acc0[2],0.f)*w0 + fmaxf(acc1[2],0.f)*w1v + fmaxf(acc2[2],0.f)*w2v + fmaxf(acc3[2],0.f)*w3v;
    float p3 = fmaxf(acc0[3],0.f)*w0 + fmaxf(acc1[3],0.f)*w1v + fmaxf(acc2[3],0.f)*w2v + fmaxf(acc3[3],0.f)*w3v;
    #pragma unroll
    for (int m = 1; m < 16; m <<= 1){
      p0 += __shfl_xor(p0, m, 64);
      p1 += __shfl_xor(p1, m, 64);
      p2 += __shfl_xor(p2, m, 64);
      p3 += __shfl_xor(p3, m, 64);
    }
    if (l15 == 0){
      int base = i0 + q * 4;
      if (base + 0 < cnt) s_lds[base + 0] = p0 + b2v;
      if (base + 1 < cnt) s_lds[base + 1] = p1 + b2v;
      if (base + 2 < cnt) s_lds[base + 2] = p2 + b2v;
      if (base + 3 < cnt) s_lds[base + 3] = p3 + b2v;
    }
  }
}

__global__ __launch_bounds__(256, 3)
void attn_pool_kernel(const float* __restrict__ x, const float* __restrict__ u,
                      const int* __restrict__ batch, const float* __restrict__ W1,
                      const float* __restrict__ b1, const float* __restrict__ W2,
                      const float* __restrict__ b2,
                      float* __restrict__ pooled_out, float* __restrict__ attn_out){
  __shared__ alignas(16) __bf16 x_lds[XMAX * XSTR];
  __shared__ alignas(16) __bf16 w1t[HID * XSTR];
  __shared__ float s_lds[XMAX];
  __shared__ float w2l[HID];
  __shared__ float hb_l[HID];
  __shared__ float red[4];
  const int tid = threadIdx.x;
  const int g = blockIdx.x;

  int start = lower_bound_i(batch, N_NODES_C, g);
  int endi  = lower_bound_i(batch, N_NODES_C, g + 1);
  const int c = endi - start;

  for (int idx = tid; idx < NF * HID; idx += 256){
    int k = idx >> 6, n = idx & 63;
    w1t[n * XSTR + k] = (__bf16)W1[k * HID + n];
  }
  if (tid < HID){
    w2l[tid] = W2[tid];
    float h = b1[tid];
    const float* ug = u + (size_t)g * GF;
    #pragma unroll 8
    for (int k = 0; k < GF; k++) h += ug[k] * W1[(NF + k) * HID + tid];
    hb_l[tid] = h;
  }
  const float b2v = b2[0];
  const floatx4* x4 = (const floatx4*)x;

  if (c <= XMAX){
    load_x_chunk(x4, start, c, x_lds, tid);
    __syncthreads();
    compute_s_chunk(x_lds, w1t, hb_l, w2l, b2v, s_lds, c, tid);
    __syncthreads();
    float lm = -INFINITY;
    for (int i = tid; i < c; i += 256) lm = fmaxf(lm, s_lds[i]);
    lm = block_max(lm, red, tid);
    float ls = 0.f;
    for (int i = tid; i < c; i += 256){ float e = __expf(s_lds[i] - lm); s_lds[i] = e; ls += e; }
    float zz = block_sum(ls, red, tid);
    float rz = 1.f / zz;
    for (int i = tid; i < c; i += 256){ float a2 = s_lds[i] * rz; s_lds[i] = a2; attn_out[start + i] = a2; }
    __syncthreads();
    {
      const int f2 = tid & 63;
      const int grp = tid >> 6;
      float p0 = 0.f, p1 = 0.f;
      for (int i = grp; i < c; i += 4){
        float a2 = s_lds[i];
        unsigned w = *(const unsigned*)(x_lds + i * XSTR + 2 * f2);
        p0 = fmaf(a2, __uint_as_float(w << 16), p0);
        p1 = fmaf(a2, __uint_as_float(w & 0xffff0000u), p1);
      }
      float* pool_red = (float*)w1t;
      pool_red[grp * NF + 2 * f2]     = p0;
      pool_red[grp * NF + 2 * f2 + 1] = p1;
      __syncthreads();
      if (tid < NF){
        float p = (pool_red[tid] + pool_red[NF + tid]) +
                  (pool_red[2 * NF + tid] + pool_red[3 * NF + tid]);
        pooled_out[(size_t)g * NF + tid] = p;
      }
    }
  } else {
    float m_run = -INFINITY;
    for (int i0 = 0; i0 < c; i0 += XMAX){
      int cc = min(XMAX, c - i0);
      __syncthreads();
      load_x_chunk(x4, start + i0, cc, x_lds, tid);
      __syncthreads();
      compute_s_chunk(x_lds, w1t, hb_l, w2l, b2v, s_lds, cc, tid);
      __syncthreads();
      float lm = -INFINITY;
      for (int i = tid; i < cc; i += 256) lm = fmaxf(lm, s_lds[i]);
      m_run = fmaxf(m_run, block_max(lm, red, tid));
    }
    float z_run = 0.f;
    for (int i0 = 0; i0 < c; i0 += XMAX){
      int cc = min(XMAX, c - i0);
      __syncthreads();
      load_x_chunk(x4, start + i0, cc, x_lds, tid);
      __syncthreads();
      compute_s_chunk(x_lds, w1t, hb_l, w2l, b2v, s_lds, cc, tid);
      __syncthreads();
      float ls = 0.f;
      for (int i = tid; i < cc; i += 256) ls += __expf(s_lds[i] - m_run);
      z_run += block_sum(ls, red, tid);
    }
    float rz = 1.f / z_run;
    float p = 0.f;
    for (int i0 = 0; i0 < c; i0 += XMAX){
      int cc = min(XMAX, c - i0);
      __syncthreads();
      load_x_chunk(x4, start + i0, cc, x_lds, tid);
      __syncthreads();
      compute_s_chunk(x_lds, w1t, hb_l, w2l, b2v, s_lds, cc, tid);
      __syncthreads();
      for (int i = tid; i < cc; i += 256){
        float a2 = __expf(s_lds[i] - m_run) * rz;
        s_lds[i] = a2;
        attn_out[start + i0 + i] = a2;
      }
      __syncthreads();
      if (tid < NF) for (int i = 0; i < cc; i++) p += s_lds[i] * (float)x_lds[i * XSTR + tid];
    }
    if (tid < NF) pooled_out[(size_t)g * NF + tid] = p;
  }
}

// ---------------- launch ----------------

extern "C" void kernel_launch(void* const* d_in, const int* in_sizes, int n_in,
                              void* d_out, int out_size, void* d_ws, size_t ws_size,
                              hipStream_t stream) {
  const float* x     = (const float*)d_in[0];
  const float* u     = (const float*)d_in[1];
  const int*   batch = (const int*)d_in[2];
  const float* W1    = (const float*)d_in[3];
  const float* b1    = (const float*)d_in[4];
  const float* W2    = (const float*)d_in[5];
  const float* b2    = (const float*)d_in[6];
  float* pooled_out = (float*)d_out;
  float* attn_out   = pooled_out + (size_t)N_GRAPHS_C * NF;

  // ws carve: [w1t bf16 16K][z f32 64K][Npool f32 8M][hbase f32 4M]
  const size_t w1t_off = 0;
  const size_t z_off   = 16384;
  const size_t N_off   = 81920;
  const size_t hb_off  = 8470528;
  const size_t need    = hb_off + (size_t)N_GRAPHS_C * HID * sizeof(float); // ~12.7 MB

  if (ws_size >= need){
    __bf16* g_w1t = (__bf16*)((char*)d_ws + w1t_off);
    float*  zbuf  = (float*)((char*)d_ws + z_off);
    float*  Npool = (float*)((char*)d_ws + N_off);
    float*  hbase = (float*)((char*)d_ws + hb_off);

    // one kernel: zero z+Npool (2064 blocks) + w1t transpose (32) + hbase (4096)
    prep_fused_kernel<<<6192, 256, 0, stream>>>(u, W1, b1,
        (floatx4*)((char*)d_ws + z_off), g_w1t, hbase);

    scores_kernel<<<(N_NODES_C + TB - 1) / TB, 256, 0, stream>>>(
        x, batch, g_w1t, hbase, W2, b2, zbuf, Npool, attn_out);

    // one kernel: attn divide (3907 blocks) + pooled divide (8192 blocks)
    finalize_fused_kernel<<<12099, 256, 0, stream>>>(batch, zbuf, Npool,
                                                     attn_out, pooled_out);
  } else {
    attn_pool_kernel<<<N_GRAPHS_C, 256, 0, stream>>>(x, u, batch, W1, b1, W2, b2,
                                                     pooled_out, attn_out);
  }
}